// Round 5
// baseline (63.187 us; speedup 1.0000x reference)
//
#include <hip/hip_runtime.h>

#define H 1024
#define L 512
#define V 50257
#define LOGIT_BLOCKS 2048   // 4 waves each -> 8192 waves = 32/CU
#define ATTN_BLOCKS 128     // 8 attn_applied cols per block
#define COLS 8

__device__ __forceinline__ float dot4(float4 a, float4 b) {
    return a.x*b.x + a.y*b.y + a.z*b.z + a.w*b.w;
}

__device__ __forceinline__ float wave_reduce_sum(float v) {
    #pragma unroll
    for (int o = 32; o > 0; o >>= 1) v += __shfl_xor(v, o, 64);
    return v;
}

// D1: all input-only GEMVs + zero xacc.
//   task <  512          : scores[task] = attn_w[task,:H].e + attn_w[task,H:].h0 + attn_b
//   512 <= task < 3584   : gh[j] = w_hh[j].h0 + b_hh[j]
//   3584 <= task < 4608  : ce[h] = comb_w[h,:H].e + comb_b[h]    (bias folded)
//   task == 4608         : xacc[0..H) = 0
__global__ void k_pre(const float* __restrict__ emb, const int* __restrict__ input,
                      const float* __restrict__ hidden, const float* __restrict__ attn_w,
                      const float* __restrict__ attn_b, const float* __restrict__ w_hh,
                      const float* __restrict__ b_hh, const float* __restrict__ comb_w,
                      const float* __restrict__ comb_b,
                      float* __restrict__ scores, float* __restrict__ gh,
                      float* __restrict__ ce, float* __restrict__ xacc) {
    __shared__ float red[4];
    int task = blockIdx.x, t = threadIdx.x, lane = t & 63, wid = t >> 6;
    if (task == 4608) {
        ((float4*)xacc)[t] = make_float4(0.f, 0.f, 0.f, 0.f);
        return;
    }
    size_t erow = (size_t)input[0] * H;
    float acc;
    if (task < 512) {
        const float4* w = (const float4*)(attn_w + (size_t)task * (2 * H));
        acc = dot4(w[t], ((const float4*)(emb + erow))[t])
            + dot4(w[256 + t], ((const float4*)hidden)[t]);
    } else if (task < 3584) {
        int j = task - 512;
        acc = dot4(((const float4*)(w_hh + (size_t)j * H))[t], ((const float4*)hidden)[t]);
    } else {
        int h = task - 3584;
        acc = dot4(((const float4*)(comb_w + (size_t)h * (2 * H)))[t], ((const float4*)(emb + erow))[t]);
    }
    acc = wave_reduce_sum(acc);
    if (lane == 0) red[wid] = acc;
    __syncthreads();
    if (t == 0) {
        float s = red[0] + red[1] + red[2] + red[3];
        if (task < 512)       scores[task] = s + attn_b[task];
        else if (task < 3584) { int j = task - 512; gh[j] = s + b_hh[j]; }
        else                  { int h = task - 3584; ce[h] = s + comb_b[h]; }
    }
}

// D2: softmax(scores) (replicated per block; block 0 writes attnw), then this
// block's 8 attn_applied cols, then partial x contribution via atomicAdd:
//   xacc[h] += sum_{k in my 8 cols} comb_w[h, H+k] * aa[k]
__global__ void k_attn_fused(const float* __restrict__ scores, const float* __restrict__ enc,
                             const float* __restrict__ comb_w,
                             float* __restrict__ attn_out, float* __restrict__ xacc) {
    __shared__ float w[512];
    __shared__ float red[4];
    __shared__ float s_acc[256];
    __shared__ float sM, sS;
    int t = threadIdx.x, lane = t & 63, wid = t >> 6, b = blockIdx.x;
    float s0 = scores[t], s1 = scores[t + 256];
    float m = fmaxf(s0, s1);
    #pragma unroll
    for (int o = 32; o > 0; o >>= 1) m = fmaxf(m, __shfl_xor(m, o, 64));
    if (lane == 0) red[wid] = m;
    __syncthreads();
    if (t == 0) sM = fmaxf(fmaxf(red[0], red[1]), fmaxf(red[2], red[3]));
    __syncthreads();
    float M = sM;
    float e0 = expf(s0 - M), e1 = expf(s1 - M);
    float ssum = wave_reduce_sum(e0 + e1);
    if (lane == 0) red[wid] = ssum;
    __syncthreads();
    if (t == 0) sS = red[0] + red[1] + red[2] + red[3];
    __syncthreads();
    float inv = 1.f / sS;
    w[t] = e0 * inv; w[t + 256] = e1 * inv;
    __syncthreads();
    if (b == 0) { attn_out[t] = w[t]; attn_out[t + 256] = w[t + 256]; }
    // aa for this block's 8 columns
    int col0 = b * COLS;
    int c  = t & 7;        // col within chunk
    int rc = t >> 3;       // row chunk 0..31
    float acc = 0.f;
    #pragma unroll 4
    for (int l = rc; l < 512; l += 32) acc += w[l] * enc[(size_t)l * H + col0 + c];
    s_acc[t] = acc;
    __syncthreads();
    #pragma unroll
    for (int st = 128; st >= 8; st >>= 1) {
        if (t < st) s_acc[t] += s_acc[t + st];
        __syncthreads();
    }
    // s_acc[0..7] = aa chunk; multiply against comb_w2 columns, accumulate to xacc
    float4 aa0 = make_float4(s_acc[0], s_acc[1], s_acc[2], s_acc[3]);
    float4 aa1 = make_float4(s_acc[4], s_acc[5], s_acc[6], s_acc[7]);
    #pragma unroll
    for (int i = 0; i < 4; ++i) {
        int h = t + 256 * i;
        const float4* c2 = (const float4*)(comb_w + (size_t)h * (2 * H) + H + col0);
        float p = dot4(c2[0], aa0) + dot4(c2[1], aa1);
        atomicAdd(&xacc[h], p);
    }
}

// D3: x = relu(xacc + ce) elementwise, then gi triple + GRU gating -> hnew[h]
__global__ void k_gru3(const float* __restrict__ w_ih, const float* __restrict__ b_ih,
                       const float* __restrict__ gh, const float* __restrict__ xacc,
                       const float* __restrict__ ce, const float* __restrict__ hidden,
                       float* __restrict__ hnew) {
    __shared__ float red[12];
    int h = blockIdx.x, t = threadIdx.x, lane = t & 63, wid = t >> 6;
    float4 xa = ((const float4*)xacc)[t];
    float4 cv = ((const float4*)ce)[t];
    float4 xv;
    xv.x = fmaxf(xa.x + cv.x, 0.f);
    xv.y = fmaxf(xa.y + cv.y, 0.f);
    xv.z = fmaxf(xa.z + cv.z, 0.f);
    xv.w = fmaxf(xa.w + cv.w, 0.f);
    float a0 = dot4(((const float4*)(w_ih + (size_t)h * H))[t], xv);
    float a1 = dot4(((const float4*)(w_ih + (size_t)(H + h) * H))[t], xv);
    float a2 = dot4(((const float4*)(w_ih + (size_t)(2 * H + h) * H))[t], xv);
    a0 = wave_reduce_sum(a0);
    a1 = wave_reduce_sum(a1);
    a2 = wave_reduce_sum(a2);
    if (lane == 0) { red[wid * 3] = a0; red[wid * 3 + 1] = a1; red[wid * 3 + 2] = a2; }
    __syncthreads();
    if (t == 0) {
        float g0 = 0.f, g1 = 0.f, g2 = 0.f;
        #pragma unroll
        for (int w2 = 0; w2 < 4; ++w2) {
            g0 += red[w2 * 3]; g1 += red[w2 * 3 + 1]; g2 += red[w2 * 3 + 2];
        }
        float r = 1.f / (1.f + expf(-(g0 + b_ih[h] + gh[h])));
        float z = 1.f / (1.f + expf(-(g1 + b_ih[H + h] + gh[H + h])));
        float n = tanhf(g2 + b_ih[2 * H + h] + r * gh[2 * H + h]);
        hnew[h] = (1.f - z) * n + z * hidden[h];
    }
}

// D4: logits + per-block online (m, sumexp) partials
__global__ void k_logits_lse(const float* __restrict__ out_w, const float* __restrict__ out_b,
                             const float* __restrict__ hvec, float* __restrict__ logits,
                             float* __restrict__ mpart, float* __restrict__ spart) {
    __shared__ float lm[4], ls[4];
    int lane = threadIdx.x & 63, wid = threadIdx.x >> 6;
    int gwave = blockIdx.x * 4 + wid;
    const int nwaves = LOGIT_BLOCKS * 4;
    float4 h4[4];
    #pragma unroll
    for (int j = 0; j < 4; ++j) h4[j] = ((const float4*)hvec)[j * 64 + lane];
    float m = -INFINITY, s = 0.f;
    for (int r = gwave; r < V; r += nwaves) {
        const float4* row = (const float4*)(out_w + (size_t)r * H);
        float acc = 0.f;
        #pragma unroll
        for (int j = 0; j < 4; ++j) acc += dot4(row[j * 64 + lane], h4[j]);
        acc = wave_reduce_sum(acc);
        float logit = acc + out_b[r];
        if (lane == 0) logits[r] = logit;
        if (logit > m) { s = s * expf(m - logit) + 1.f; m = logit; }
        else           { s += expf(logit - m); }
    }
    if (lane == 0) { lm[wid] = m; ls[wid] = s; }
    __syncthreads();
    if (threadIdx.x == 0) {
        float M = fmaxf(fmaxf(lm[0], lm[1]), fmaxf(lm[2], lm[3]));
        float S = 0.f;
        if (M > -INFINITY) {
            #pragma unroll
            for (int i = 0; i < 4; ++i) S += ls[i] * expf(lm[i] - M);
        }
        mpart[blockIdx.x] = M; spart[blockIdx.x] = S;
    }
}

// D5: every block merges the 2048 partials, then subtracts logZ in place
__global__ void k_finalize(const float* __restrict__ mpart, const float* __restrict__ spart,
                           float* __restrict__ out) {
    __shared__ float lm[4], ls[4];
    __shared__ float sLogZ;
    int t = threadIdx.x, lane = t & 63, wid = t >> 6;
    float m = -INFINITY, s = 0.f;
    for (int i = t; i < LOGIT_BLOCKS; i += 256) {
        float m2 = mpart[i], s2 = spart[i];
        float mm = fmaxf(m, m2);
        if (mm > -INFINITY) s = s * expf(m - mm) + s2 * expf(m2 - mm);
        m = mm;
    }
    #pragma unroll
    for (int o = 32; o > 0; o >>= 1) {
        float m2 = __shfl_xor(m, o, 64), s2 = __shfl_xor(s, o, 64);
        float mm = fmaxf(m, m2);
        if (mm > -INFINITY) s = s * expf(m - mm) + s2 * expf(m2 - mm);
        m = mm;
    }
    if (lane == 0) { lm[wid] = m; ls[wid] = s; }
    __syncthreads();
    if (t == 0) {
        float M = fmaxf(fmaxf(lm[0], lm[1]), fmaxf(lm[2], lm[3]));
        float S = 0.f;
        #pragma unroll
        for (int i = 0; i < 4; ++i) S += ls[i] * expf(lm[i] - M);
        sLogZ = M + logf(S);
    }
    __syncthreads();
    int v = blockIdx.x * 256 + t;
    if (v < V) out[v] -= sLogZ;
}

extern "C" void kernel_launch(void* const* d_in, const int* in_sizes, int n_in,
                              void* d_out, int out_size, void* d_ws, size_t ws_size,
                              hipStream_t stream) {
    const int*   input  = (const int*)  d_in[0];
    const float* hidden = (const float*)d_in[1];
    const float* enc    = (const float*)d_in[2];
    const float* emb    = (const float*)d_in[3];
    const float* attn_w = (const float*)d_in[4];
    const float* attn_b = (const float*)d_in[5];
    const float* comb_w = (const float*)d_in[6];
    const float* comb_b = (const float*)d_in[7];
    const float* w_ih   = (const float*)d_in[8];
    const float* w_hh   = (const float*)d_in[9];
    const float* b_ih   = (const float*)d_in[10];
    const float* b_hh   = (const float*)d_in[11];
    const float* out_w  = (const float*)d_in[12];
    const float* out_b  = (const float*)d_in[13];

    float* out   = (float*)d_out;            // [0, V)      log_softmax
    float* hnew  = out + V;                  // [V, V+H)    h_new
    float* attnw = out + V + H;              // [V+H, +L)   attn_weights

    float* ws     = (float*)d_ws;
    float* scores = ws;                      // 512
    float* gh     = ws + 512;                // 3072
    float* ce     = ws + 3584;               // 1024 (includes comb_b)
    float* xacc   = ws + 4608;               // 1024 (zeroed by D1 each call)
    float* mpart  = ws + 5632;               // 2048
    float* spart  = ws + 7680;               // 2048

    k_pre        <<<4609, 256, 0, stream>>>(emb, input, hidden, attn_w, attn_b,
                                            w_hh, b_hh, comb_w, comb_b, scores, gh, ce, xacc);
    k_attn_fused <<<ATTN_BLOCKS, 256, 0, stream>>>(scores, enc, comb_w, attnw, xacc);
    k_gru3       <<<1024, 256, 0, stream>>>(w_ih, b_ih, gh, xacc, ce, hidden, hnew);
    k_logits_lse <<<LOGIT_BLOCKS, 256, 0, stream>>>(out_w, out_b, hnew, out, mpart, spart);
    k_finalize   <<<(V + 255) / 256, 256, 0, stream>>>(mpart, spart, out);
}